// Round 1
// baseline (10749.304 us; speedup 1.0000x reference)
//
#include <hip/hip_runtime.h>
#include <cstdint>
#include <cstddef>

#define BATCH   8192
#define INDIM   64
#define OUTDIM  64
#define HID     128
#define NG      512        // 4*HID gates
#define BT      32         // batch tile per block
#define NT      256        // threads per block
#define KC      16         // K rows per weight chunk
#define K0      192        // INDIM + HID
#define K1      256        // HID + HID

// packed weight layout in d_ws (float offsets)
#define OFF_W0  0
#define OFF_B0  (K0*NG)                 // 98304
#define OFF_W1  (OFF_B0 + NG)           // 98816
#define OFF_B1  (OFF_W1 + K1*NG)        // 229888
#define OFF_WD  (OFF_B1 + NG)           // 230400
#define OFF_BD  (OFF_WD + HID*OUTDIM)   // 238592
#define PACKN   (OFF_BD + OUTDIM)       // 238656 floats ~ 933 KB

// LDS layout (floats)
#define AX_F    ((INDIM + HID + HID) * BT)   // 320*32 = 10240  (x | h0 | h1), [k][sample]
#define WBHALF  (KC * NG)                    // 8192 floats = 32 KB per buffer
#define SMEM_F  (AX_F + 2 * WBHALF)          // 26624 floats
#define SMEM_B  (SMEM_F * 4)                 // 106496 bytes

typedef __attribute__((address_space(1))) const unsigned int as1_cuint;
typedef __attribute__((address_space(3))) unsigned int as3_uint;

__device__ __forceinline__ void gl_lds16(const float* g, float* l) {
  // async global->LDS, 16B per lane; LDS dest = wave-uniform base + lane*16
  __builtin_amdgcn_global_load_lds((as1_cuint*)g, (as3_uint*)l, 16, 0, 0);
}

__device__ __forceinline__ float fsig(float x) {
  return 1.0f / (1.0f + __expf(-x));
}
__device__ __forceinline__ float ftanh(float x) {
  float e = __expf(2.0f * x);
  return 1.0f - 2.0f / (e + 1.0f);
}

// stage one 32 KB contiguous chunk (8192 floats) global->LDS, all 256 threads
__device__ __forceinline__ void stage32k(const float* __restrict__ src, float* dst,
                                         int wave, int lane) {
#pragma unroll
  for (int i = 0; i < 8; ++i) {
    int base = wave * 512 + i * 64;          // 16B-unit index, wave-uniform
    gl_lds16(src + (size_t)(base + lane) * 4, dst + (size_t)base * 4);
  }
}

// gates GEMM: acc[8 samples][8 packed-gate cols] += A[k][s] * Wt[k][gp]
// A: LDS, rows (c*KC+kk), cols BT samples. W streamed global->LDS double-buffered.
__device__ __forceinline__ void run_gemm(const float* __restrict__ wsrc, const float* A,
                                         float* WB, int nchunks, int wave, int lane,
                                         int s0, int gp0, float (&acc)[64]) {
  stage32k(wsrc, WB, wave, lane);
  for (int c = 0; c < nchunks; ++c) {
    float* cur = WB + (c & 1) * WBHALF;
    __syncthreads();   // chunk c resident (vmcnt drain) + everyone done with the other buffer
    if (c + 1 < nchunks) {
      float* nxt = WB + ((c + 1) & 1) * WBHALF;
      stage32k(wsrc + (size_t)(c + 1) * WBHALF, nxt, wave, lane);
    }
#pragma unroll
    for (int kk = 0; kk < KC; ++kk) {
      const float4* ap = (const float4*)(A + (c * KC + kk) * BT + s0);
      float4 a0 = ap[0];
      float4 a1 = ap[1];
      const float4* wp = (const float4*)(cur + kk * NG + gp0);
      float4 w0 = wp[0];
      float4 w1 = wp[1];
      float av[8] = {a0.x, a0.y, a0.z, a0.w, a1.x, a1.y, a1.z, a1.w};
      float wv[8] = {w0.x, w0.y, w0.z, w0.w, w1.x, w1.y, w1.z, w1.w};
#pragma unroll
      for (int r = 0; r < 8; ++r) {
#pragma unroll
        for (int q = 0; q < 8; ++q) {
          acc[r * 8 + q] = fmaf(av[r], wv[q], acc[r * 8 + q]);
        }
      }
    }
  }
}

__global__ __launch_bounds__(NT, 1) void lstm_kernel(
    const float* __restrict__ x, const float* __restrict__ pk,
    float* __restrict__ out, int S, int P) {
  extern __shared__ float smem[];
  float* AX = smem;           // [320][BT]
  float* WB = smem + AX_F;    // 2 x 32KB weight chunk buffers

  const int tid = threadIdx.x;
  const int wave = tid >> 6, lane = tid & 63;
  const int sg = tid & 3, cg = tid >> 2;
  const int s0 = sg * 8;           // sample offset in tile (owns s0..s0+7)
  const int gp0 = cg * 8;          // packed gate col (owns 2 hidden units x 4 gates)
  const int j0 = cg * 2;           // hidden units j0, j0+1
  const int b0 = blockIdx.x * BT;
  const int ds = tid & 31, og = tid >> 5;   // decoder mapping: sample, out-group

  for (int i = tid; i < AX_F; i += NT) AX[i] = 0.0f;   // h0 = h1 = 0

  float b0r[8], b1r[8], bdr[8];
#pragma unroll
  for (int q = 0; q < 8; ++q) {
    b0r[q] = pk[OFF_B0 + gp0 + q];
    b1r[q] = pk[OFF_B1 + gp0 + q];
    bdr[q] = pk[OFF_BD + og * 8 + q];
  }

  float c0r[16], c1r[16];   // [unit u][sample r] = u*8+r
#pragma unroll
  for (int q = 0; q < 16; ++q) { c0r[q] = 0.0f; c1r[q] = 0.0f; }

  __syncthreads();

  const int T = S + P;
  for (int step = 0; step < T; ++step) {
    if (step < S) {
      // load x_t tile, transposed store into AX rows 0..63
#pragma unroll
      for (int i = 0; i < 2; ++i) {
        int q = tid + NT * i;
        int s = q >> 4, c4 = q & 15;
        const float4 v = *(const float4*)(x + ((size_t)(b0 + s) * S + step) * INDIM + c4 * 4);
        AX[(c4 * 4 + 0) * BT + s] = v.x;
        AX[(c4 * 4 + 1) * BT + s] = v.y;
        AX[(c4 * 4 + 2) * BT + s] = v.z;
        AX[(c4 * 4 + 3) * BT + s] = v.w;
      }
    }

    // ---------------- layer 0: gates over AX rows [0,192) ----------------
    float acc[64];
#pragma unroll
    for (int r = 0; r < 8; ++r) {
#pragma unroll
      for (int q = 0; q < 8; ++q) acc[r * 8 + q] = b0r[q];
    }
    run_gemm(pk + OFF_W0, AX, WB, K0 / KC, wave, lane, s0, gp0, acc);
    __syncthreads();   // all threads done reading AX for layer0
#pragma unroll
    for (int u = 0; u < 2; ++u) {
      float h[8];
#pragma unroll
      for (int r = 0; r < 8; ++r) {
        float gi = fsig(acc[r * 8 + u * 4 + 0]);
        float gf = fsig(acc[r * 8 + u * 4 + 1]);
        float gg = ftanh(acc[r * 8 + u * 4 + 2]);
        float go = fsig(acc[r * 8 + u * 4 + 3]);
        float cn = fmaf(gf, c0r[u * 8 + r], gi * gg);
        c0r[u * 8 + r] = cn;
        h[r] = go * ftanh(cn);
      }
      float* dst = AX + (INDIM + j0 + u) * BT + s0;
      *(float4*)(dst)     = make_float4(h[0], h[1], h[2], h[3]);
      *(float4*)(dst + 4) = make_float4(h[4], h[5], h[6], h[7]);
    }
    __syncthreads();

    // ---------------- layer 1: gates over AX rows [64,320) ----------------
#pragma unroll
    for (int r = 0; r < 8; ++r) {
#pragma unroll
      for (int q = 0; q < 8; ++q) acc[r * 8 + q] = b1r[q];
    }
    run_gemm(pk + OFF_W1, AX + INDIM * BT, WB, K1 / KC, wave, lane, s0, gp0, acc);

    // prefetch W_dec into WB0 (free: last chunk c=15 computes out of WB1)
    if (step >= S) stage32k(pk + OFF_WD, WB, wave, lane);

    __syncthreads();
#pragma unroll
    for (int u = 0; u < 2; ++u) {
      float h[8];
#pragma unroll
      for (int r = 0; r < 8; ++r) {
        float gi = fsig(acc[r * 8 + u * 4 + 0]);
        float gf = fsig(acc[r * 8 + u * 4 + 1]);
        float gg = ftanh(acc[r * 8 + u * 4 + 2]);
        float go = fsig(acc[r * 8 + u * 4 + 3]);
        float cn = fmaf(gf, c1r[u * 8 + r], gi * gg);
        c1r[u * 8 + r] = cn;
        h[r] = go * ftanh(cn);
      }
      float* dst = AX + (INDIM + HID + j0 + u) * BT + s0;
      *(float4*)(dst)     = make_float4(h[0], h[1], h[2], h[3]);
      *(float4*)(dst + 4) = make_float4(h[4], h[5], h[6], h[7]);
    }
    __syncthreads();

    // ---------------- decoder projection + feedback ----------------
    if (step >= S) {
      const int dstep = step - S;
      float pacc[8];
#pragma unroll
      for (int q = 0; q < 8; ++q) pacc[q] = bdr[q];
      const float* h1base = AX + (INDIM + HID) * BT + ds;
      const float* wdb = WB + og * 8;   // W_dec^T [k][64] staged in WB0
#pragma unroll 4
      for (int k = 0; k < HID; ++k) {
        float a = h1base[k * BT];
        const float4* wp = (const float4*)(wdb + k * OUTDIM);
        float4 w0 = wp[0], w1 = wp[1];
        pacc[0] = fmaf(a, w0.x, pacc[0]);
        pacc[1] = fmaf(a, w0.y, pacc[1]);
        pacc[2] = fmaf(a, w0.z, pacc[2]);
        pacc[3] = fmaf(a, w0.w, pacc[3]);
        pacc[4] = fmaf(a, w1.x, pacc[4]);
        pacc[5] = fmaf(a, w1.y, pacc[5]);
        pacc[6] = fmaf(a, w1.z, pacc[6]);
        pacc[7] = fmaf(a, w1.w, pacc[7]);
      }
      float* op = out + ((size_t)(b0 + ds) * P + dstep) * OUTDIM + og * 8;
      *(float4*)(op)     = make_float4(pacc[0], pacc[1], pacc[2], pacc[3]);
      *(float4*)(op + 4) = make_float4(pacc[4], pacc[5], pacc[6], pacc[7]);
      // feedback: p becomes next step's input, transposed into AX rows 0..63
#pragma unroll
      for (int q = 0; q < 8; ++q) AX[(og * 8 + q) * BT + ds] = pacc[q];
      __syncthreads();   // protect WB0 (next GEMM0 stage) and AX x-rows
    }
  }
}

// pack weights: W^T [k][gate], gates interleaved gp = 4*j + type (i,f,g,o);
// biases pre-summed; W_dec transposed [k][o].
__global__ void prepack_kernel(const float* __restrict__ wih0, const float* __restrict__ whh0,
                               const float* __restrict__ bih0, const float* __restrict__ bhh0,
                               const float* __restrict__ wih1, const float* __restrict__ whh1,
                               const float* __restrict__ bih1, const float* __restrict__ bhh1,
                               const float* __restrict__ wdec, const float* __restrict__ bdec,
                               float* __restrict__ pko) {
  int idx = blockIdx.x * blockDim.x + threadIdx.x;
  if (idx >= PACKN) return;
  if (idx < OFF_B0) {                      // W0^T
    int k = idx / NG, gp = idx % NG;
    int j = gp >> 2, t = gp & 3, row = t * HID + j;
    pko[idx] = (k < INDIM) ? wih0[row * INDIM + k] : whh0[row * HID + (k - INDIM)];
  } else if (idx < OFF_W1) {               // B0 (summed)
    int gp = idx - OFF_B0;
    int j = gp >> 2, t = gp & 3, row = t * HID + j;
    pko[idx] = bih0[row] + bhh0[row];
  } else if (idx < OFF_B1) {               // W1^T
    int r = idx - OFF_W1;
    int k = r / NG, gp = r % NG;
    int j = gp >> 2, t = gp & 3, row = t * HID + j;
    pko[idx] = (k < HID) ? wih1[row * HID + k] : whh1[row * HID + (k - HID)];
  } else if (idx < OFF_WD) {               // B1 (summed)
    int gp = idx - OFF_B1;
    int j = gp >> 2, t = gp & 3, row = t * HID + j;
    pko[idx] = bih1[row] + bhh1[row];
  } else if (idx < OFF_BD) {               // W_dec^T
    int r = idx - OFF_WD;
    int k = r / OUTDIM, o = r % OUTDIM;
    pko[idx] = wdec[o * HID + k];
  } else {                                 // b_dec
    pko[idx] = bdec[idx - OFF_BD];
  }
}

extern "C" void kernel_launch(void* const* d_in, const int* in_sizes, int n_in,
                              void* d_out, int out_size, void* d_ws, size_t ws_size,
                              hipStream_t stream) {
  const float* x    = (const float*)d_in[0];
  const float* wih0 = (const float*)d_in[1];
  const float* whh0 = (const float*)d_in[2];
  const float* bih0 = (const float*)d_in[3];
  const float* bhh0 = (const float*)d_in[4];
  const float* wih1 = (const float*)d_in[5];
  const float* whh1 = (const float*)d_in[6];
  const float* bih1 = (const float*)d_in[7];
  const float* bhh1 = (const float*)d_in[8];
  const float* wdec = (const float*)d_in[9];
  const float* bdec = (const float*)d_in[10];
  float* out = (float*)d_out;
  float* pk = (float*)d_ws;

  const int S = in_sizes[0] / (BATCH * INDIM);     // 128
  const int P = out_size / (BATCH * OUTDIM);       // 20 (pred_steps)

  prepack_kernel<<<(PACKN + 255) / 256, 256, 0, stream>>>(
      wih0, whh0, bih0, bhh0, wih1, whh1, bih1, bhh1, wdec, bdec, pk);

  // allow >64KB dynamic LDS (gfx950 has 160 KiB/CU); idempotent, capture-safe
  (void)hipFuncSetAttribute((const void*)lstm_kernel,
                            hipFuncAttributeMaxDynamicSharedMemorySize, SMEM_B);

  lstm_kernel<<<BATCH / BT, NT, SMEM_B, stream>>>(x, pk, out, S, P);
}

// Round 2
// 10069.249 us; speedup vs baseline: 1.0675x; 1.0675x over previous
//
#include <hip/hip_runtime.h>
#include <cstdint>
#include <cstddef>

#define BATCH   8192
#define INDIM   64
#define OUTDIM  64
#define HID     128
#define NG      512        // 4*HID gates
#define BT      32         // batch tile per block
#define NT      256        // threads per block
#define KC      8          // K rows per weight chunk (16KB chunks -> 72KB LDS -> 2 blocks/CU)
#define K0      192        // INDIM + HID
#define K1      256        // HID + HID

// packed weight layout in d_ws (float offsets)
#define OFF_W0  0
#define OFF_B0  (K0*NG)                 // 98304
#define OFF_W1  (OFF_B0 + NG)           // 98816
#define OFF_B1  (OFF_W1 + K1*NG)        // 229888
#define OFF_WD  (OFF_B1 + NG)           // 230400
#define OFF_BD  (OFF_WD + HID*OUTDIM)   // 238592
#define PACKN   (OFF_BD + OUTDIM)       // 238656 floats ~ 933 KB

// LDS layout (floats)
#define AX_F    ((INDIM + HID + HID) * BT)   // 320*32 = 10240  (x | h0 | h1), [k][sample]
#define WBHALF  (KC * NG)                    // 4096 floats = 16 KB per buffer
#define SMEM_F  (AX_F + 2 * WBHALF)          // 18432 floats
#define SMEM_B  (SMEM_F * 4)                 // 73728 bytes -> 2 blocks/CU (147KB < 160KB)

typedef __attribute__((address_space(1))) const unsigned int as1_cuint;
typedef __attribute__((address_space(3))) unsigned int as3_uint;

__device__ __forceinline__ void gl_lds16(const float* g, float* l) {
  // async global->LDS, 16B per lane; LDS dest = wave-uniform base + lane*16
  __builtin_amdgcn_global_load_lds((as1_cuint*)g, (as3_uint*)l, 16, 0, 0);
}

__device__ __forceinline__ float fsig(float x) {
  return 1.0f / (1.0f + __expf(-x));
}
__device__ __forceinline__ float ftanh(float x) {
  float e = __expf(2.0f * x);
  return 1.0f - 2.0f / (e + 1.0f);
}

// stage one 16 KB contiguous chunk (4096 floats) global->LDS, all 256 threads
__device__ __forceinline__ void stage16k(const float* __restrict__ src, float* dst,
                                         int wave, int lane) {
#pragma unroll
  for (int i = 0; i < 4; ++i) {
    int base = i * 256 + wave * 64;          // 16B-unit index, wave-uniform
    gl_lds16(src + (size_t)(base + lane) * 4, dst + (size_t)base * 4);
  }
}

// gates GEMM: acc[8 samples][8 packed-gate cols] += A[k][s] * Wt[k][pos]
// A: LDS, rows (c*KC+kk), cols BT samples. W streamed global->LDS double-buffered.
// Thread (wave w, lane l) reads W positions w*128 + {0,64} + (l>>2)*4 + 0..3:
// per ds_read_b128, a wave covers a contiguous 256B segment (2-way bank = free).
__device__ __forceinline__ void run_gemm(const float* __restrict__ wsrc, const float* A,
                                         float* WB, int nchunks, int wave, int lane,
                                         int s0, int wq, float (&acc)[64]) {
  stage16k(wsrc, WB, wave, lane);
  for (int c = 0; c < nchunks; ++c) {
    float* cur = WB + (c & 1) * WBHALF;
    __syncthreads();   // chunk c resident (vmcnt drain) + everyone done with the other buffer
    if (c + 1 < nchunks) {
      float* nxt = WB + ((c + 1) & 1) * WBHALF;
      stage16k(wsrc + (size_t)(c + 1) * WBHALF, nxt, wave, lane);
    }
#pragma unroll
    for (int kk = 0; kk < KC; ++kk) {
      const float4* ap = (const float4*)(A + (c * KC + kk) * BT + s0);
      float4 a0 = ap[0];
      float4 a1 = ap[1];
      const float* wrow = cur + kk * NG + wq;
      float4 w0 = *(const float4*)(wrow);
      float4 w1 = *(const float4*)(wrow + 64);
      float av[8] = {a0.x, a0.y, a0.z, a0.w, a1.x, a1.y, a1.z, a1.w};
      float wv[8] = {w0.x, w0.y, w0.z, w0.w, w1.x, w1.y, w1.z, w1.w};
#pragma unroll
      for (int r = 0; r < 8; ++r) {
#pragma unroll
        for (int q = 0; q < 8; ++q) {
          acc[r * 8 + q] = fmaf(av[r], wv[q], acc[r * 8 + q]);
        }
      }
    }
  }
}

__global__ __launch_bounds__(NT, 2) void lstm_kernel(
    const float* __restrict__ x, const float* __restrict__ pk,
    float* __restrict__ out, int S, int P) {
  extern __shared__ float smem[];
  float* AX = smem;           // [320][BT]
  float* WB = smem + AX_F;    // 2 x 16KB weight chunk buffers

  const int tid = threadIdx.x;
  const int wave = tid >> 6, lane = tid & 63;
  const int lg = lane >> 2;        // 0..15 lane group
  const int s0 = (lane & 3) * 8;   // sample offset in tile (owns s0..s0+7)
  const int wq = wave * 128 + lg * 4;  // packed W position base (first half; +64 = second)
  const int j0 = wave * 32 + lg * 2;   // hidden units j0 (half=0), j0+1 (half=1)
  const int b0 = blockIdx.x * BT;
  const int ds = tid & 31, og = tid >> 5;   // decoder mapping: sample, out-group

  for (int i = tid; i < AX_F; i += NT) AX[i] = 0.0f;   // h0 = h1 = 0

  float b0r[8], b1r[8], bdr[8];
#pragma unroll
  for (int q = 0; q < 8; ++q) {
    int pos = wave * 128 + (q >> 2) * 64 + lg * 4 + (q & 3);
    b0r[q] = pk[OFF_B0 + pos];
    b1r[q] = pk[OFF_B1 + pos];
    bdr[q] = pk[OFF_BD + og * 8 + q];
  }

  float c0r[16], c1r[16];   // [unit u][sample r] = u*8+r
#pragma unroll
  for (int q = 0; q < 16; ++q) { c0r[q] = 0.0f; c1r[q] = 0.0f; }

  __syncthreads();

  const int T = S + P;
  for (int step = 0; step < T; ++step) {
    if (step < S) {
      // load x_t tile, transposed store into AX rows 0..63
#pragma unroll
      for (int i = 0; i < 2; ++i) {
        int q = tid + NT * i;
        int s = q >> 4, c4 = q & 15;
        const float4 v = *(const float4*)(x + ((size_t)(b0 + s) * S + step) * INDIM + c4 * 4);
        AX[(c4 * 4 + 0) * BT + s] = v.x;
        AX[(c4 * 4 + 1) * BT + s] = v.y;
        AX[(c4 * 4 + 2) * BT + s] = v.z;
        AX[(c4 * 4 + 3) * BT + s] = v.w;
      }
    }

    // ---------------- layer 0: gates over AX rows [0,192) ----------------
    float acc[64];
#pragma unroll
    for (int r = 0; r < 8; ++r) {
#pragma unroll
      for (int q = 0; q < 8; ++q) acc[r * 8 + q] = b0r[q];
    }
    run_gemm(pk + OFF_W0, AX, WB, K0 / KC, wave, lane, s0, wq, acc);
    __syncthreads();   // all threads done reading AX for layer0
#pragma unroll
    for (int u = 0; u < 2; ++u) {
      float h[8];
#pragma unroll
      for (int r = 0; r < 8; ++r) {
        float gi = fsig(acc[r * 8 + u * 4 + 0]);
        float gf = fsig(acc[r * 8 + u * 4 + 1]);
        float gg = ftanh(acc[r * 8 + u * 4 + 2]);
        float go = fsig(acc[r * 8 + u * 4 + 3]);
        float cn = fmaf(gf, c0r[u * 8 + r], gi * gg);
        c0r[u * 8 + r] = cn;
        h[r] = go * ftanh(cn);
      }
      float* dst = AX + (INDIM + j0 + u) * BT + s0;
      *(float4*)(dst)     = make_float4(h[0], h[1], h[2], h[3]);
      *(float4*)(dst + 4) = make_float4(h[4], h[5], h[6], h[7]);
    }
    __syncthreads();

    // ---------------- layer 1: gates over AX rows [64,320) ----------------
#pragma unroll
    for (int r = 0; r < 8; ++r) {
#pragma unroll
      for (int q = 0; q < 8; ++q) acc[r * 8 + q] = b1r[q];
    }
    run_gemm(pk + OFF_W1, AX + INDIM * BT, WB, K1 / KC, wave, lane, s0, wq, acc);
    __syncthreads();
#pragma unroll
    for (int u = 0; u < 2; ++u) {
      float h[8];
#pragma unroll
      for (int r = 0; r < 8; ++r) {
        float gi = fsig(acc[r * 8 + u * 4 + 0]);
        float gf = fsig(acc[r * 8 + u * 4 + 1]);
        float gg = ftanh(acc[r * 8 + u * 4 + 2]);
        float go = fsig(acc[r * 8 + u * 4 + 3]);
        float cn = fmaf(gf, c1r[u * 8 + r], gi * gg);
        c1r[u * 8 + r] = cn;
        h[r] = go * ftanh(cn);
      }
      float* dst = AX + (INDIM + HID + j0 + u) * BT + s0;
      *(float4*)(dst)     = make_float4(h[0], h[1], h[2], h[3]);
      *(float4*)(dst + 4) = make_float4(h[4], h[5], h[6], h[7]);
    }
    __syncthreads();

    // ---------------- decoder projection + feedback ----------------
    if (step >= S) {
      const int dstep = step - S;
      float pacc[8];
#pragma unroll
      for (int q = 0; q < 8; ++q) pacc[q] = bdr[q];
      const float* h1base = AX + (INDIM + HID) * BT + ds;
      const float* wdb = pk + OFF_WD + og * 8;   // W_dec^T [k][64], L2-resident
#pragma unroll 8
      for (int k = 0; k < HID; ++k) {
        float a = h1base[k * BT];
        const float4* wp = (const float4*)(wdb + k * OUTDIM);
        float4 w0 = wp[0], w1 = wp[1];
        pacc[0] = fmaf(a, w0.x, pacc[0]);
        pacc[1] = fmaf(a, w0.y, pacc[1]);
        pacc[2] = fmaf(a, w0.z, pacc[2]);
        pacc[3] = fmaf(a, w0.w, pacc[3]);
        pacc[4] = fmaf(a, w1.x, pacc[4]);
        pacc[5] = fmaf(a, w1.y, pacc[5]);
        pacc[6] = fmaf(a, w1.z, pacc[6]);
        pacc[7] = fmaf(a, w1.w, pacc[7]);
      }
      float* op = out + ((size_t)(b0 + ds) * P + dstep) * OUTDIM + og * 8;
      *(float4*)(op)     = make_float4(pacc[0], pacc[1], pacc[2], pacc[3]);
      *(float4*)(op + 4) = make_float4(pacc[4], pacc[5], pacc[6], pacc[7]);
      // feedback: p becomes next step's input, transposed into AX rows 0..63
#pragma unroll
      for (int q = 0; q < 8; ++q) AX[(og * 8 + q) * BT + ds] = pacc[q];
      __syncthreads();   // protect AX x-rows before next step's GEMM0
    }
  }
}

// pack weights with the conflict-free column permutation:
// packed position p in a 512-float row: w = p>>7, half = (p>>6)&1,
// lg = (p>>2)&15, t = p&3  ->  hidden unit j = w*32 + lg*2 + half,
// original gate row = t*HID + j (PyTorch i,f,g,o order). Biases pre-summed,
// same permutation. W_dec transposed [k][o].
__global__ void prepack_kernel(const float* __restrict__ wih0, const float* __restrict__ whh0,
                               const float* __restrict__ bih0, const float* __restrict__ bhh0,
                               const float* __restrict__ wih1, const float* __restrict__ whh1,
                               const float* __restrict__ bih1, const float* __restrict__ bhh1,
                               const float* __restrict__ wdec, const float* __restrict__ bdec,
                               float* __restrict__ pko) {
  int idx = blockIdx.x * blockDim.x + threadIdx.x;
  if (idx >= PACKN) return;
  if (idx < OFF_B0) {                      // W0^T permuted
    int k = idx / NG, p = idx % NG;
    int w = p >> 7, half = (p >> 6) & 1, lg = (p >> 2) & 15, t = p & 3;
    int j = w * 32 + lg * 2 + half, row = t * HID + j;
    pko[idx] = (k < INDIM) ? wih0[row * INDIM + k] : whh0[row * HID + (k - INDIM)];
  } else if (idx < OFF_W1) {               // B0 (summed, permuted)
    int p = idx - OFF_B0;
    int w = p >> 7, half = (p >> 6) & 1, lg = (p >> 2) & 15, t = p & 3;
    int j = w * 32 + lg * 2 + half, row = t * HID + j;
    pko[idx] = bih0[row] + bhh0[row];
  } else if (idx < OFF_B1) {               // W1^T permuted
    int r = idx - OFF_W1;
    int k = r / NG, p = r % NG;
    int w = p >> 7, half = (p >> 6) & 1, lg = (p >> 2) & 15, t = p & 3;
    int j = w * 32 + lg * 2 + half, row = t * HID + j;
    pko[idx] = (k < HID) ? wih1[row * HID + k] : whh1[row * HID + (k - HID)];
  } else if (idx < OFF_WD) {               // B1 (summed, permuted)
    int p = idx - OFF_B1;
    int w = p >> 7, half = (p >> 6) & 1, lg = (p >> 2) & 15, t = p & 3;
    int j = w * 32 + lg * 2 + half, row = t * HID + j;
    pko[idx] = bih1[row] + bhh1[row];
  } else if (idx < OFF_BD) {               // W_dec^T
    int r = idx - OFF_WD;
    int k = r / OUTDIM, o = r % OUTDIM;
    pko[idx] = wdec[o * HID + k];
  } else {                                 // b_dec
    pko[idx] = bdec[idx - OFF_BD];
  }
}

extern "C" void kernel_launch(void* const* d_in, const int* in_sizes, int n_in,
                              void* d_out, int out_size, void* d_ws, size_t ws_size,
                              hipStream_t stream) {
  const float* x    = (const float*)d_in[0];
  const float* wih0 = (const float*)d_in[1];
  const float* whh0 = (const float*)d_in[2];
  const float* bih0 = (const float*)d_in[3];
  const float* bhh0 = (const float*)d_in[4];
  const float* wih1 = (const float*)d_in[5];
  const float* whh1 = (const float*)d_in[6];
  const float* bih1 = (const float*)d_in[7];
  const float* bhh1 = (const float*)d_in[8];
  const float* wdec = (const float*)d_in[9];
  const float* bdec = (const float*)d_in[10];
  float* out = (float*)d_out;
  float* pk = (float*)d_ws;

  const int S = in_sizes[0] / (BATCH * INDIM);     // 128
  const int P = out_size / (BATCH * OUTDIM);       // 20 (pred_steps)

  prepack_kernel<<<(PACKN + 255) / 256, 256, 0, stream>>>(
      wih0, whh0, bih0, bhh0, wih1, whh1, bih1, bhh1, wdec, bdec, pk);

  // allow >64KB dynamic LDS (gfx950 has 160 KiB/CU); idempotent, capture-safe
  (void)hipFuncSetAttribute((const void*)lstm_kernel,
                            hipFuncAttributeMaxDynamicSharedMemorySize, SMEM_B);

  lstm_kernel<<<BATCH / BT, NT, SMEM_B, stream>>>(x, pk, out, S, P);
}

// Round 3
// 8151.008 us; speedup vs baseline: 1.3188x; 1.2353x over previous
//
#include <hip/hip_runtime.h>
#include <cstdint>
#include <cstddef>

#define BATCH   8192
#define INDIM   64
#define OUTDIM  64
#define HID     128
#define NG      512        // 4*HID gates
#define BT      32         // batch tile per block
#define NT      256        // threads per block
#define K0      192        // INDIM + HID
#define K1      256        // HID + HID

// packed weight layout in d_ws (float offsets)
#define OFF_W0  0
#define OFF_B0  (K0*NG)                 // 98304
#define OFF_W1  (OFF_B0 + NG)           // 98816
#define OFF_B1  (OFF_W1 + K1*NG)        // 229888
#define OFF_WD  (OFF_B1 + NG)           // 230400
#define OFF_BD  (OFF_WD + HID*OUTDIM)   // 238592
#define PACKN   (OFF_BD + OUTDIM)       // 238656 floats ~ 933 KB

#define AX_F    ((INDIM + HID + HID) * BT)   // 320*32 = 10240 floats = 40KB LDS

__device__ __forceinline__ float fsig(float x) {
  return 1.0f / (1.0f + __expf(-x));
}
__device__ __forceinline__ float ftanh(float x) {
  float e = __expf(2.0f * x);
  return 1.0f - 2.0f / (e + 1.0f);
}

__device__ __forceinline__ void fma8x8(const float4& a0, const float4& a1,
                                       const float4& w0, const float4& w1,
                                       float (&acc)[64]) {
  const float av[8] = {a0.x, a0.y, a0.z, a0.w, a1.x, a1.y, a1.z, a1.w};
  const float wv[8] = {w0.x, w0.y, w0.z, w0.w, w1.x, w1.y, w1.z, w1.w};
#pragma unroll
  for (int r = 0; r < 8; ++r)
#pragma unroll
    for (int q = 0; q < 8; ++q)
      acc[r * 8 + q] = fmaf(av[r], wv[q], acc[r * 8 + q]);
}

// gates GEMM: acc[8 samples][8 gate cols] += A[k][s] * Wt[k][gp0..gp0+8)
// W streamed global(L2)->registers, ping-pong 4-row buffers, depth-4 prefetch.
// wt = pk + OFF + gp0 (thread-private column slice, 32B contiguous per row).
// Overreads up to 8 rows past K land in the following pk regions (safe, unused).
template <int K>
__device__ __forceinline__ void run_gemm(const float* __restrict__ wt,
                                         const float* __restrict__ A,
                                         int s0, float (&acc)[64]) {
  float4 wa[4][2], wb[4][2];
#pragma unroll
  for (int r = 0; r < 4; ++r) {
    wa[r][0] = *(const float4*)(wt + r * NG);
    wa[r][1] = *(const float4*)(wt + r * NG + 4);
  }
  const float* wp = wt + 4 * NG;
  const float* ap = A + s0;
  for (int k = 0; k < K; k += 8) {
    // load rows k+4..k+7, compute rows k..k+3 from wa
#pragma unroll
    for (int r = 0; r < 4; ++r) {
      wb[r][0] = *(const float4*)(wp + r * NG);
      wb[r][1] = *(const float4*)(wp + r * NG + 4);
    }
    wp += 4 * NG;
#pragma unroll
    for (int r = 0; r < 4; ++r) {
      const float4 a0 = *(const float4*)(ap + r * BT);
      const float4 a1 = *(const float4*)(ap + r * BT + 4);
      fma8x8(a0, a1, wa[r][0], wa[r][1], acc);
    }
    ap += 4 * BT;
    // load rows k+8..k+11, compute rows k+4..k+7 from wb
#pragma unroll
    for (int r = 0; r < 4; ++r) {
      wa[r][0] = *(const float4*)(wp + r * NG);
      wa[r][1] = *(const float4*)(wp + r * NG + 4);
    }
    wp += 4 * NG;
#pragma unroll
    for (int r = 0; r < 4; ++r) {
      const float4 a0 = *(const float4*)(ap + r * BT);
      const float4 a1 = *(const float4*)(ap + r * BT + 4);
      fma8x8(a0, a1, wb[r][0], wb[r][1], acc);
    }
    ap += 4 * BT;
  }
}

__global__ __launch_bounds__(NT, 1) void lstm_kernel(
    const float* __restrict__ x, const float* __restrict__ pk,
    float* __restrict__ out, int S, int P) {
  __shared__ float AX[AX_F];   // [320 rows][BT samples]: x | h0 | h1

  const int tid = threadIdx.x;
  const int s0 = (tid & 3) * 8;        // sample offset (owns s0..s0+7)
  const int gp0 = (tid >> 2) * 8;      // gate col base (2 hidden units x i,f,g,o)
  const int j0 = gp0 >> 2;             // hidden units j0, j0+1
  const int b0 = blockIdx.x * BT;
  const int ds = tid & 31, og = tid >> 5;   // decoder mapping: sample, out-group

  for (int i = tid; i < AX_F; i += NT) AX[i] = 0.0f;   // h0 = h1 = 0

  float b0r[8], b1r[8], bdr[8];
#pragma unroll
  for (int q = 0; q < 8; ++q) {
    b0r[q] = pk[OFF_B0 + gp0 + q];
    b1r[q] = pk[OFF_B1 + gp0 + q];
    bdr[q] = pk[OFF_BD + og * 8 + q];
  }

  float c0r[16], c1r[16];   // [unit u][sample r] = u*8+r
#pragma unroll
  for (int q = 0; q < 16; ++q) { c0r[q] = 0.0f; c1r[q] = 0.0f; }

  __syncthreads();

  const int T = S + P;
  for (int step = 0; step < T; ++step) {
    if (step < S) {
      // load x_t tile, transposed store into AX rows 0..63
#pragma unroll
      for (int i = 0; i < 2; ++i) {
        int q = tid + NT * i;
        int s = q >> 4, c4 = q & 15;
        const float4 v = *(const float4*)(x + ((size_t)(b0 + s) * S + step) * INDIM + c4 * 4);
        AX[(c4 * 4 + 0) * BT + s] = v.x;
        AX[(c4 * 4 + 1) * BT + s] = v.y;
        AX[(c4 * 4 + 2) * BT + s] = v.z;
        AX[(c4 * 4 + 3) * BT + s] = v.w;
      }
    }
    __syncthreads();   // B1: x-store / decoder feedback / prev h-stores visible

    // ---------------- layer 0: gates over AX rows [0,192) ----------------
    float acc[64];
#pragma unroll
    for (int r = 0; r < 8; ++r)
#pragma unroll
      for (int q = 0; q < 8; ++q) acc[r * 8 + q] = b0r[q];
    run_gemm<K0>(pk + OFF_W0 + gp0, AX, s0, acc);
    __syncthreads();   // B2: all GEMM0 reads done before h0 rows overwritten
#pragma unroll
    for (int u = 0; u < 2; ++u) {
      float h[8];
#pragma unroll
      for (int r = 0; r < 8; ++r) {
        float gi = fsig(acc[r * 8 + u * 4 + 0]);
        float gf = fsig(acc[r * 8 + u * 4 + 1]);
        float gg = ftanh(acc[r * 8 + u * 4 + 2]);
        float go = fsig(acc[r * 8 + u * 4 + 3]);
        float cn = fmaf(gf, c0r[u * 8 + r], gi * gg);
        c0r[u * 8 + r] = cn;
        h[r] = go * ftanh(cn);
      }
      float* dst = AX + (INDIM + j0 + u) * BT + s0;
      *(float4*)(dst)     = make_float4(h[0], h[1], h[2], h[3]);
      *(float4*)(dst + 4) = make_float4(h[4], h[5], h[6], h[7]);
    }
    __syncthreads();   // B3: h0 visible

    // ---------------- layer 1: gates over AX rows [64,320) ----------------
#pragma unroll
    for (int r = 0; r < 8; ++r)
#pragma unroll
      for (int q = 0; q < 8; ++q) acc[r * 8 + q] = b1r[q];
    run_gemm<K1>(pk + OFF_W1 + gp0, AX + INDIM * BT, s0, acc);
    __syncthreads();   // B4: all GEMM1 reads done before h1 rows overwritten
#pragma unroll
    for (int u = 0; u < 2; ++u) {
      float h[8];
#pragma unroll
      for (int r = 0; r < 8; ++r) {
        float gi = fsig(acc[r * 8 + u * 4 + 0]);
        float gf = fsig(acc[r * 8 + u * 4 + 1]);
        float gg = ftanh(acc[r * 8 + u * 4 + 2]);
        float go = fsig(acc[r * 8 + u * 4 + 3]);
        float cn = fmaf(gf, c1r[u * 8 + r], gi * gg);
        c1r[u * 8 + r] = cn;
        h[r] = go * ftanh(cn);
      }
      float* dst = AX + (INDIM + HID + j0 + u) * BT + s0;
      *(float4*)(dst)     = make_float4(h[0], h[1], h[2], h[3]);
      *(float4*)(dst + 4) = make_float4(h[4], h[5], h[6], h[7]);
    }

    // ---------------- decoder projection + feedback ----------------
    if (step >= S) {
      __syncthreads();   // B5: h1 visible
      const int dstep = step - S;
      float pacc[8];
#pragma unroll
      for (int q = 0; q < 8; ++q) pacc[q] = bdr[q];
      const float* h1base = AX + (INDIM + HID) * BT + ds;
      const float* wdb = pk + OFF_WD + og * 8;   // W_dec^T [k][64], L2-resident
#pragma unroll 8
      for (int k = 0; k < HID; ++k) {
        float a = h1base[k * BT];
        const float4* wp = (const float4*)(wdb + k * OUTDIM);
        float4 w0 = wp[0], w1 = wp[1];
        pacc[0] = fmaf(a, w0.x, pacc[0]);
        pacc[1] = fmaf(a, w0.y, pacc[1]);
        pacc[2] = fmaf(a, w0.z, pacc[2]);
        pacc[3] = fmaf(a, w0.w, pacc[3]);
        pacc[4] = fmaf(a, w1.x, pacc[4]);
        pacc[5] = fmaf(a, w1.y, pacc[5]);
        pacc[6] = fmaf(a, w1.z, pacc[6]);
        pacc[7] = fmaf(a, w1.w, pacc[7]);
      }
      float* op = out + ((size_t)(b0 + ds) * P + dstep) * OUTDIM + og * 8;
      *(float4*)(op)     = make_float4(pacc[0], pacc[1], pacc[2], pacc[3]);
      *(float4*)(op + 4) = make_float4(pacc[4], pacc[5], pacc[6], pacc[7]);
      // feedback: p becomes next step's input, transposed into AX rows 0..63
#pragma unroll
      for (int q = 0; q < 8; ++q) AX[(og * 8 + q) * BT + ds] = pacc[q];
      // next-step B1 makes feedback visible before GEMM0
    }
  }
}

// pack weights: W^T [k][gate], gates interleaved gp = 4*j + type (i,f,g,o);
// biases pre-summed; W_dec transposed [k][o].
__global__ void prepack_kernel(const float* __restrict__ wih0, const float* __restrict__ whh0,
                               const float* __restrict__ bih0, const float* __restrict__ bhh0,
                               const float* __restrict__ wih1, const float* __restrict__ whh1,
                               const float* __restrict__ bih1, const float* __restrict__ bhh1,
                               const float* __restrict__ wdec, const float* __restrict__ bdec,
                               float* __restrict__ pko) {
  int idx = blockIdx.x * blockDim.x + threadIdx.x;
  if (idx >= PACKN) return;
  if (idx < OFF_B0) {                      // W0^T
    int k = idx / NG, gp = idx % NG;
    int j = gp >> 2, t = gp & 3, row = t * HID + j;
    pko[idx] = (k < INDIM) ? wih0[row * INDIM + k] : whh0[row * HID + (k - INDIM)];
  } else if (idx < OFF_W1) {               // B0 (summed)
    int gp = idx - OFF_B0;
    int j = gp >> 2, t = gp & 3, row = t * HID + j;
    pko[idx] = bih0[row] + bhh0[row];
  } else if (idx < OFF_B1) {               // W1^T
    int r = idx - OFF_W1;
    int k = r / NG, gp = r % NG;
    int j = gp >> 2, t = gp & 3, row = t * HID + j;
    pko[idx] = (k < HID) ? wih1[row * HID + k] : whh1[row * HID + (k - HID)];
  } else if (idx < OFF_WD) {               // B1 (summed)
    int gp = idx - OFF_B1;
    int j = gp >> 2, t = gp & 3, row = t * HID + j;
    pko[idx] = bih1[row] + bhh1[row];
  } else if (idx < OFF_BD) {               // W_dec^T
    int r = idx - OFF_WD;
    int k = r / OUTDIM, o = r % OUTDIM;
    pko[idx] = wdec[o * HID + k];
  } else {                                 // b_dec
    pko[idx] = bdec[idx - OFF_BD];
  }
}

extern "C" void kernel_launch(void* const* d_in, const int* in_sizes, int n_in,
                              void* d_out, int out_size, void* d_ws, size_t ws_size,
                              hipStream_t stream) {
  const float* x    = (const float*)d_in[0];
  const float* wih0 = (const float*)d_in[1];
  const float* whh0 = (const float*)d_in[2];
  const float* bih0 = (const float*)d_in[3];
  const float* bhh0 = (const float*)d_in[4];
  const float* wih1 = (const float*)d_in[5];
  const float* whh1 = (const float*)d_in[6];
  const float* bih1 = (const float*)d_in[7];
  const float* bhh1 = (const float*)d_in[8];
  const float* wdec = (const float*)d_in[9];
  const float* bdec = (const float*)d_in[10];
  float* out = (float*)d_out;
  float* pk = (float*)d_ws;

  const int S = in_sizes[0] / (BATCH * INDIM);     // 128
  const int P = out_size / (BATCH * OUTDIM);       // 20 (pred_steps)

  prepack_kernel<<<(PACKN + 255) / 256, 256, 0, stream>>>(
      wih0, whh0, bih0, bhh0, wih1, whh1, bih1, bhh1, wdec, bdec, pk);

  lstm_kernel<<<BATCH / BT, NT, 0, stream>>>(x, pk, out, S, P);
}